// Round 2
// baseline (191.040 us; speedup 1.0000x reference)
//
#include <hip/hip_runtime.h>

// mean(|convdata[:,:,3] - output[:,:,3]|) over B=64, S=100, K=4, H=W=32 fp32.
// Channel-3 slice of pair p = b*S+s is the contiguous 1024-float (4 KB) chunk
// at float offset p*4096 + 3072  (float4 offset p*1024 + 768).
// Total reduced elements: 6400 * 1024 = 6,553,600.  Useful HBM read: 52.4 MB.
//
// Single fused kernel: 1600 blocks x 256 threads, 4 chunks (pairs) per block,
// each thread does 8 fully-unrolled independent float4 loads (2 tensors x 4
// chunks), wave64 shuffle reduce -> LDS cross-wave -> one atomicAdd per block
// into d_out (pre-zeroed by a 4-byte memset node in the graph).

#define PAIRS_TOTAL 6400
#define PAIRS_PER_BLOCK 4
#define NBLOCKS (PAIRS_TOTAL / PAIRS_PER_BLOCK)   // 1600
#define NTHREADS 256

__global__ __launch_bounds__(NTHREADS)
void absdiff_mean_fused_kernel(const float4* __restrict__ outp,
                               const float4* __restrict__ conv,
                               float* __restrict__ out,
                               float inv_total) {
    const int t = threadIdx.x;
    // float4 index of this thread's element in chunk 0 of this block
    const size_t base = (size_t)blockIdx.x * (PAIRS_PER_BLOCK * 1024) + 768 + t;

    float4 a[PAIRS_PER_BLOCK], b[PAIRS_PER_BLOCK];
    #pragma unroll
    for (int c = 0; c < PAIRS_PER_BLOCK; ++c) {
        const size_t g = base + (size_t)c * 1024;
        a[c] = outp[g];          // 8 independent global_load_dwordx4,
        b[c] = conv[g];          // all issued before any use (vmcnt pipelining)
    }

    float acc = 0.0f;
    #pragma unroll
    for (int c = 0; c < PAIRS_PER_BLOCK; ++c) {
        acc += fabsf(b[c].x - a[c].x) + fabsf(b[c].y - a[c].y)
             + fabsf(b[c].z - a[c].z) + fabsf(b[c].w - a[c].w);
    }

    // wave64 shuffle reduction
    #pragma unroll
    for (int off = 32; off > 0; off >>= 1)
        acc += __shfl_down(acc, off, 64);

    __shared__ float smem[NTHREADS / 64];
    const int lane = t & 63;
    const int wave = t >> 6;
    if (lane == 0) smem[wave] = acc;
    __syncthreads();

    if (t == 0) {
        float s = 0.0f;
        #pragma unroll
        for (int w = 0; w < NTHREADS / 64; ++w) s += smem[w];
        atomicAdd(out, s * inv_total);   // device-scope by default on CDNA
    }
}

extern "C" void kernel_launch(void* const* d_in, const int* in_sizes, int n_in,
                              void* d_out, int out_size, void* d_ws, size_t ws_size,
                              hipStream_t stream) {
    const float4* outp = (const float4*)d_in[0];   // "output"
    const float4* conv = (const float4*)d_in[1];   // "convdata"
    float* out = (float*)d_out;

    const float inv_total = 1.0f / (float)(PAIRS_TOTAL * 1024);

    // d_out is poisoned (0xAA) before every timed launch — zero it with a
    // graph-capturable 4-byte memset node, then accumulate atomically.
    hipMemsetAsync(out, 0, sizeof(float), stream);
    absdiff_mean_fused_kernel<<<NBLOCKS, NTHREADS, 0, stream>>>(outp, conv, out, inv_total);
}

// Round 4
// 183.095 us; speedup vs baseline: 1.0434x; 1.0434x over previous
//
#include <hip/hip_runtime.h>

// mean(|convdata[:,:,3] - output[:,:,3]|) over B=64, S=100, K=4, H=W=32 fp32.
// Channel-3 slice of pair p = b*S+s is the contiguous 1024-float (4 KB) chunk
// at float offset p*4096 + 3072  (float4 offset p*1024 + 768).
// Total: 6400 pairs * 1024 elems = 6,553,600.  Useful HBM read: 52.4 MB.
// Roofline: 52.4 MB / 6.3 TB/s ~= 8.3 us kernel-side; measured envelope is
// dominated by harness poison/restore (~165 us) — see R1-R3 journal.
//
// Structure (R1-proven): two plain dispatches, no memset node, no atomics,
// no cooperative launch (cooperative launches fail graph capture here — R3).
// Kernel 1: 1600 blocks x 256 threads, static partition, 4 pairs per block,
//           8 fully-unrolled independent float4 loads per thread.
// Kernel 2: single block reduces the 1600 partials from d_ws.

#define PAIRS_TOTAL 6400
#define PAIRS_PER_BLOCK 4
#define NBLOCKS (PAIRS_TOTAL / PAIRS_PER_BLOCK)   // 1600
#define NTHREADS 256

__global__ __launch_bounds__(NTHREADS)
void absdiff_partial_kernel(const float4* __restrict__ outp,
                            const float4* __restrict__ conv,
                            float* __restrict__ partials) {
    const int t = threadIdx.x;
    const size_t base = (size_t)blockIdx.x * (PAIRS_PER_BLOCK * 1024) + 768 + t;

    float4 a[PAIRS_PER_BLOCK], b[PAIRS_PER_BLOCK];
    #pragma unroll
    for (int c = 0; c < PAIRS_PER_BLOCK; ++c) {
        const size_t g = base + (size_t)c * 1024;
        a[c] = outp[g];          // 8 independent global_load_dwordx4 in flight
        b[c] = conv[g];
    }

    float acc = 0.0f;
    #pragma unroll
    for (int c = 0; c < PAIRS_PER_BLOCK; ++c) {
        acc += fabsf(b[c].x - a[c].x) + fabsf(b[c].y - a[c].y)
             + fabsf(b[c].z - a[c].z) + fabsf(b[c].w - a[c].w);
    }

    // wave64 shuffle reduction
    #pragma unroll
    for (int off = 32; off > 0; off >>= 1)
        acc += __shfl_down(acc, off, 64);

    __shared__ float smem[NTHREADS / 64];
    const int lane = t & 63;
    const int wave = t >> 6;
    if (lane == 0) smem[wave] = acc;
    __syncthreads();

    if (t == 0) {
        float s = 0.0f;
        #pragma unroll
        for (int w = 0; w < NTHREADS / 64; ++w) s += smem[w];
        partials[blockIdx.x] = s;
    }
}

__global__ __launch_bounds__(NTHREADS)
void final_reduce_kernel(const float* __restrict__ partials,
                         float* __restrict__ out,
                         float inv_total) {
    const int t = threadIdx.x;
    float acc = 0.0f;
    for (int i = t; i < NBLOCKS; i += NTHREADS) acc += partials[i];
    #pragma unroll
    for (int off = 32; off > 0; off >>= 1)
        acc += __shfl_down(acc, off, 64);
    __shared__ float smem[NTHREADS / 64];
    const int lane = t & 63;
    const int wave = t >> 6;
    if (lane == 0) smem[wave] = acc;
    __syncthreads();
    if (t == 0) {
        float s = 0.0f;
        #pragma unroll
        for (int w = 0; w < NTHREADS / 64; ++w) s += smem[w];
        out[0] = s * inv_total;
    }
}

extern "C" void kernel_launch(void* const* d_in, const int* in_sizes, int n_in,
                              void* d_out, int out_size, void* d_ws, size_t ws_size,
                              hipStream_t stream) {
    const float4* outp = (const float4*)d_in[0];   // "output"
    const float4* conv = (const float4*)d_in[1];   // "convdata"
    float* partials = (float*)d_ws;                // 1600 floats (6.4 KB)
    float* out = (float*)d_out;
    const float inv_total = 1.0f / (float)(PAIRS_TOTAL * 1024);

    absdiff_partial_kernel<<<NBLOCKS, NTHREADS, 0, stream>>>(outp, conv, partials);
    final_reduce_kernel<<<1, NTHREADS, 0, stream>>>(partials, out, inv_total);
}